// Round 1
// baseline (444.498 us; speedup 1.0000x reference)
//
#include <hip/hip_runtime.h>

#define FLOW_DEPTH 8
#define BLOCK 64        // threads == atoms per block; single wave per block
#define W_F4 18         // float4 per atom in w (72 floats = 288 B)
#define B_F4 6          // float4 per atom in b (24 floats = 96 B)
#define CH   65         // padded LDS chunk stride in float4 (64 data + 1 pad)
#define Z_OFF ((W_F4 - 1) * CH + BLOCK)   // 1169: z region start (64 float4)

typedef const __attribute__((address_space(1))) void g_void;
typedef __attribute__((address_space(3))) void l_void;

// w staged via global_load_lds DMA, 18 chunks of 64 float4, chunk-stride 65
// float4 (pad BETWEEN chunks -- compatible with DMA's wave-uniform-base +
// lane*16 layout). Readback addr for atom a elem j: i=18a+j -> sw[i + (i>>6)],
// bank-group (i+i>>6)%8 spreads over all 8 groups (vs 4 unpadded = 16-way).
// z ALSO staged via one DMA chunk (48 f4 of data; lanes 48-63 clamp-duplicate
// lane 47's source so exec stays full and no OOB read on the last block).
// b is NOT staged (direct per-thread global loads, L1 absorbs). LDS = 19.3 KiB
// -> still 8 single-wave blocks/CU. Outputs staged through LDS (reusing the w
// region, dead after fragment readback) so each lane issues exactly ONE
// coalesced float4 store: lanes 0-47 cover the [64,3] z rows (768 B), lanes
// 48-63 cover the 64 logdet floats (256 B). Single wave: no __syncthreads,
// just s_waitcnt lgkmcnt(0) between ds_write and cross-lane ds_read.
__global__ __launch_bounds__(BLOCK) void graphflow_kernel(
    const float* __restrict__ z_in,
    const float* __restrict__ w,
    const float* __restrict__ b,
    float* __restrict__ out,
    int n_atoms)
{
    __shared__ float4 sw[Z_OFF + BLOCK];   // 1233 f4 = 19.3 KiB

    const int t = threadIdx.x;            // lane id == atom-within-block
    const int atom0 = blockIdx.x * BLOCK;
    const int n = atom0 + t;

    const float4* gw = reinterpret_cast<const float4*>(w) + (size_t)atom0 * W_F4;
    const bool full = (atom0 + BLOCK <= n_atoms);

    float z0 = 0.f, z1 = 0.f, z2 = 0.f;

    if (full) {
        // Coalesced DMA: chunk k -> LDS base sw + k*CH (+ lane*16 implicit).
#pragma unroll
        for (int k = 0; k < W_F4; ++k) {
            __builtin_amdgcn_global_load_lds((g_void*)(gw + k * BLOCK + t),
                                             (l_void*)(sw + k * CH), 16, 0, 0);
        }
        // z chunk: 48 real float4 (192 floats = 64 atoms * 3). Per-lane global
        // source is free-form (only the LDS dest is wave-uniform+lane*16), so
        // clamp lanes 48-63 to lane 47's source: full exec, no OOB, dup lands
        // in sw[Z_OFF+48..63] and is never read.
        const float4* gz = reinterpret_cast<const float4*>(z_in) + (size_t)atom0 * 3 / 4;
        const int tz = (t < 47) ? t : 47;
        __builtin_amdgcn_global_load_lds((g_void*)(gz + tz),
                                         (l_void*)(sw + Z_OFF), 16, 0, 0);
    } else {
        // Partial tail block (not hit for N=1e6): regular loads, scalar z.
        int nw = (n_atoms - atom0) * W_F4;
        for (int k = 0; k < W_F4; ++k) {
            int idx = k * BLOCK + t;
            if (idx < nw) sw[idx + (idx >> 6)] = gw[idx];
        }
        __syncthreads();   // block-uniform branch; cheap for one wave
        if (n < n_atoms) {
            z0 = z_in[n * 3 + 0];
            z1 = z_in[n * 3 + 1];
            z2 = z_in[n * 3 + 2];
        }
    }

    // Issue b loads while the DMA is in flight.
    float4 br[B_F4];
    if (n < n_atoms) {
        const float4* gb = reinterpret_cast<const float4*>(b) + (size_t)n * B_F4;
#pragma unroll
        for (int j = 0; j < B_F4; ++j) br[j] = gb[j];
    }

    __builtin_amdgcn_s_waitcnt(0);   // drain DMA before LDS reads

    if (n >= n_atoms) return;

    if (full) {
        const float* s_z = reinterpret_cast<const float*>(sw + Z_OFF);
        z0 = s_z[3 * t + 0];
        z1 = s_z[3 * t + 1];
        z2 = s_z[3 * t + 2];
    }

    // LDS -> registers: atom t's 18 w-float4s from the padded layout.
    float4 wr[W_F4];
#pragma unroll
    for (int j = 0; j < W_F4; ++j) {
        int i = t * W_F4 + j;
        wr[j] = sw[i + (i >> 6)];
    }

    const float* wf = reinterpret_cast<const float*>(wr);
    const float* bf = reinterpret_cast<const float*>(br);

    float logdet = 0.0f;

#pragma unroll
    for (int d = 0; d < FLOW_DEPTH; ++d) {
        const float* W = wf + d * 9;
        float w00 = W[0], w01 = W[1], w02 = W[2];
        float w10 = W[3], w11 = W[4], w12 = W[5];
        float w20 = W[6], w21 = W[7], w22 = W[8];

        // D = |diag| + 0.1 ; log-det uses |0.1 + diag| (faithful to ref).
        float d0 = fabsf(w00) + 0.1f;
        float d1 = fabsf(w11) + 0.1f;
        float d2 = fabsf(w22) + 0.1f;
        // sum of 3 logs = log of |product|; one v_log_f32 instead of three.
        logdet += __logf(fabsf((0.1f + w00) * (0.1f + w11) * (0.1f + w22)));

        // M = L @ (D @ U), L = strict-lower + I, U = strict-upper + I
        float m01 = d0 * w01;
        float m02 = d0 * w02;
        float m12 = d1 * w12;
        float M00 = d0;
        float M01 = m01;
        float M02 = m02;
        float M10 = w10 * d0;
        float M11 = fmaf(w10, m01, d1);
        float M12 = fmaf(w10, m02, m12);
        float M20 = w20 * d0;
        float M21 = fmaf(w20, m01, w21 * d1);
        float M22 = fmaf(w20, m02, fmaf(w21, m12, d2));

        // z = z @ M + b[d]
        float t0 = fmaf(z0, M00, fmaf(z1, M10, fmaf(z2, M20, bf[d * 3 + 0])));
        float t1 = fmaf(z0, M01, fmaf(z1, M11, fmaf(z2, M21, bf[d * 3 + 1])));
        float t2 = fmaf(z0, M02, fmaf(z1, M12, fmaf(z2, M22, bf[d * 3 + 2])));

        // z = z @ perms[d % 3]
        int p = d % 3;
        if (p == 0) {            // P_XY
            z0 = t1; z1 = t0; z2 = t2;
        } else if (p == 1) {     // P_YZ
            z0 = t2; z1 = t0; z2 = t1;
        } else {                 // P_XZ
            z0 = t2; z1 = t1; z2 = t0;
        }
    }

    if (full) {
        // Coalesced epilogue: stage [64,3] z rows + 64 logdets as 64 float4 in
        // LDS (w region is dead), one float4 store per lane.
        float* s_o = reinterpret_cast<float*>(sw);
        s_o[3 * t + 0] = z0;
        s_o[3 * t + 1] = z1;
        s_o[3 * t + 2] = z2;
        s_o[192 + t]   = logdet;
        asm volatile("s_waitcnt lgkmcnt(0)" ::: "memory");  // cross-lane LDS dep
        const float4* s_o4 = reinterpret_cast<const float4*>(s_o);
        if (t < 48) {
            float4* oz = reinterpret_cast<float4*>(out) + (size_t)atom0 * 3 / 4;
            oz[t] = s_o4[t];                         // 768 B contiguous
        } else {
            float4* ol = reinterpret_cast<float4*>(out + (size_t)3 * n_atoms)
                         + (atom0 >> 2);
            ol[t - 48] = s_o4[t];                    // 256 B contiguous
        }
    } else {
        out[n * 3 + 0] = z0;
        out[n * 3 + 1] = z1;
        out[n * 3 + 2] = z2;
        out[(size_t)3 * n_atoms + n] = logdet;
    }
}

extern "C" void kernel_launch(void* const* d_in, const int* in_sizes, int n_in,
                              void* d_out, int out_size, void* d_ws, size_t ws_size,
                              hipStream_t stream) {
    const float* z = (const float*)d_in[0];
    const float* w = (const float*)d_in[1];
    const float* b = (const float*)d_in[2];
    float* out = (float*)d_out;

    int n_atoms = in_sizes[0] / 3;  // z is [N,3]
    int grid = (n_atoms + BLOCK - 1) / BLOCK;

    hipLaunchKernelGGL(graphflow_kernel, dim3(grid), dim3(BLOCK), 0, stream,
                       z, w, b, out, n_atoms);
}